// Round 3
// baseline (739.612 us; speedup 1.0000x reference)
//
#include <hip/hip_runtime.h>
#include <hip/hip_bf16.h>
#include <math.h>

#define TT 128
#define VV 25

typedef __attribute__((ext_vector_type(8))) short bf16x8;
typedef __attribute__((ext_vector_type(4))) float f32x4;

__device__ inline unsigned short f2bf(float f) {
    __hip_bfloat16 h = __float2bfloat16(f);
    return __builtin_bit_cast(unsigned short, h);
}

// LDS map (floats):
//   xv   [25][68] f32      @ 0     (1700)   lives whole block (residual)
//   scb  sc[64]|bi[64]     @ 1700  (128)
//   U = @1840:
//     yn   [25][64] f32    @ U+0    (1600)  dead after qk
//     qkb  [25][52] f32    @ U+1600 (1300)  dead after dots
//     Abuf [3][25][25] f32 @ U+2900 (1875)  dead after softmax
//     A_bf [80][40] u16    @ U+0    (1600)  overlays yn
//     xvT  [64][40] u16    @ U+1600 (1280)  overlays qkb
//     zA   [32][200] u16   @ U+2912 (3200)  overlays Abuf
// total = 1840 + 6112 = 7952 floats = 31808 B  -> 5 blocks/CU
#define LDS_FLOATS 7952

__global__ __launch_bounds__(256, 4)
void agcn_fused_kernel(const float* __restrict__ x,
                       const float* __restrict__ PA,
                       const float* __restrict__ ln_g, const float* __restrict__ ln_b,
                       const float* __restrict__ Wqk, const float* __restrict__ bqk,
                       const float* __restrict__ conv_w, const float* __restrict__ conv_b,
                       const float* __restrict__ bn_g, const float* __restrict__ bn_b,
                       const float* __restrict__ bn_m, const float* __restrict__ bn_v,
                       float* __restrict__ out)
{
    __shared__ float lds[LDS_FLOATS];
    float* xv  = lds;                // [25][68]
    float* scb = lds + 1700;         // sc|bi
    float* U   = lds + 1840;
    float* yn   = U;                 // [25][64]
    float* qkb  = U + 1600;          // [25][52]
    float* Abuf = U + 2900;          // [3][625]
    unsigned short* A_bf = (unsigned short*)U;            // [80][40]
    unsigned short* xvT  = (unsigned short*)(U + 1600);   // [64][40]
    unsigned short* zA   = (unsigned short*)(U + 2912);   // [32][200]

    const int bid = blockIdx.x;
    const int n = bid >> 7, t = bid & 127;
    const int tid = threadIdx.x;
    const int lane = tid & 63, w = tid >> 6;
    const int g = lane >> 4, l15 = lane & 15;

    // ---- phase 0: stage BN params + x tile ----
    if (tid < 64) {
        float sc = bn_g[tid] * rsqrtf(bn_v[tid] + 1e-5f);
        float cb = conv_b[tid] + conv_b[64 + tid] + conv_b[128 + tid];
        scb[tid] = sc;
        scb[64 + tid] = cb * sc + bn_b[tid] - bn_m[tid] * sc;
    }
    const float* xbase = x + (size_t)n * 204800 + t * 25;
    for (int idx = tid; idx < 1600; idx += 256) {
        int c = idx / 25, v = idx - c * 25;          // v fastest -> coalesced
        xv[v * 68 + c] = xbase[c * 3200 + v];
    }
    __syncthreads();

    // ---- phase 1: LayerNorm (wave per joint stripe) ----
    for (int v = w; v < VV; v += 4) {
        float val = xv[v * 68 + lane];
        float s = val;
        for (int off = 32; off; off >>= 1) s += __shfl_xor(s, off);
        float mu = s * (1.0f / 64.0f);
        float d = val - mu;
        float s2 = d * d;
        for (int off = 32; off; off >>= 1) s2 += __shfl_xor(s2, off);
        float rstd = rsqrtf(s2 * (1.0f / 64.0f) + 1e-5f);
        yn[v * 64 + lane] = d * rstd * ln_g[lane] + ln_b[lane];
    }
    __syncthreads();

    // ---- phase 2: qk = yn @ Wqk^T + bqk (Wqk rows straight from global/L1) ----
    for (int idx = tid; idx < 1200; idx += 256) {
        int v = idx / 48, j = idx - v * 48;
        const float4* yr = (const float4*)&yn[v * 64];
        const float4* wr = (const float4*)&Wqk[j * 64];
        float acc = bqk[j];
        #pragma unroll
        for (int c4 = 0; c4 < 16; ++c4) {
            float4 a = yr[c4], b = wr[c4];
            acc += a.x * b.x + a.y * b.y + a.z * b.z + a.w * b.w;
        }
        qkb[v * 52 + j] = acc;
    }
    __syncthreads();

    // ---- phase 3: dots ----
    for (int idx = tid; idx < 1875; idx += 256) {
        int h = idx / 625, r = idx - h * 625;
        int i = r / 25, j = r - i * 25;
        const float4* q = (const float4*)&qkb[i * 52 + h * 8];
        const float4* k = (const float4*)&qkb[j * 52 + 24 + h * 8];
        float4 q0 = q[0], q1 = q[1], k0 = k[0], k1 = k[1];
        float d = q0.x * k0.x + q0.y * k0.y + q0.z * k0.z + q0.w * k0.w
                + q1.x * k1.x + q1.y * k1.y + q1.z * k1.z + q1.w * k1.w;
        Abuf[idx] = d * 0.35355339059327373f;
    }
    __syncthreads();

    // ---- phase 4: softmax*PA -> A_bf (bf16, K-pad zeroed); xv -> xvT bf16 ----
    if (tid < 75) {
        int h = tid / 25, i = tid - h * 25;
        const float* row = &Abuf[h * 625 + i * 25];
        const float* pa = &PA[h * 625 + i * 25];
        float m = row[0];
        #pragma unroll
        for (int j = 1; j < VV; ++j) m = fmaxf(m, row[j]);
        float e[VV];
        float s = 0.f;
        #pragma unroll
        for (int j = 0; j < VV; ++j) { e[j] = __expf(row[j] - m); s += e[j]; }
        float inv = 1.0f / s;
        unsigned short* ar = &A_bf[(h * 25 + i) * 40];
        #pragma unroll
        for (int j = 0; j < VV; ++j) ar[j] = f2bf(e[j] * inv * pa[j]);
        #pragma unroll
        for (int j = VV; j < 32; ++j) ar[j] = 0;
    }
    for (int idx = tid; idx < 2560; idx += 256) {
        int c = idx / 40, j = idx - c * 40;
        float val = (j < VV) ? xv[j * 68 + c] : 0.f;   // zero K-pad (and tail)
        xvT[idx] = f2bf(val);
    }
    __syncthreads();

    // ---- phase 5: z MFMA  z[r=h*25+i][c] = sum_j A[r][j] * xv[j][c] ----
    // wave w owns col-tile nt=w (c = 16w+l15); 5 row-tiles
    {
        bf16x8 bfrag = *(bf16x8*)&xvT[(16 * w + l15) * 40 + 8 * g];
        #pragma unroll
        for (int mt = 0; mt < 5; ++mt) {
            bf16x8 afrag = *(bf16x8*)&A_bf[(16 * mt + l15) * 40 + 8 * g];
            f32x4 zacc = {0.f, 0.f, 0.f, 0.f};
            zacc = __builtin_amdgcn_mfma_f32_16x16x32_bf16(afrag, bfrag, zacc, 0, 0, 0);
            #pragma unroll
            for (int reg = 0; reg < 4; ++reg) {
                int r = 16 * mt + 4 * g + reg;
                if (r < 75) {
                    int h = r / 25, i = r - h * 25;
                    zA[i * 200 + h * 64 + 16 * w + l15] = f2bf(zacc[reg]);
                }
            }
        }
    }
    __syncthreads();

    // ---- phase 6: conv MFMA out[v][o] = sum_k zA[v][k] * W[k][o] + epilogue ----
    // wave w owns o-tile nt=w (o = 16w+l15); B-frags from GLOBAL conv_w (L2-hot)
    {
        const int o = 16 * w + l15;
        f32x4 acc0 = {0.f, 0.f, 0.f, 0.f}, acc1 = {0.f, 0.f, 0.f, 0.f};
        #pragma unroll
        for (int kt = 0; kt < 6; ++kt) {
            int h = kt >> 1;
            int cc0 = (kt & 1) * 32 + 8 * g;
            const float4* wp = (const float4*)&conv_w[h * 4096 + o * 64 + cc0];
            float4 w0 = wp[0], w1 = wp[1];
            bf16x8 bfr;
            bfr[0] = (short)f2bf(w0.x); bfr[1] = (short)f2bf(w0.y);
            bfr[2] = (short)f2bf(w0.z); bfr[3] = (short)f2bf(w0.w);
            bfr[4] = (short)f2bf(w1.x); bfr[5] = (short)f2bf(w1.y);
            bfr[6] = (short)f2bf(w1.z); bfr[7] = (short)f2bf(w1.w);
            bf16x8 a0 = *(bf16x8*)&zA[l15 * 200 + 32 * kt + 8 * g];
            bf16x8 a1 = *(bf16x8*)&zA[(16 + l15) * 200 + 32 * kt + 8 * g];
            acc0 = __builtin_amdgcn_mfma_f32_16x16x32_bf16(a0, bfr, acc0, 0, 0, 0);
            acc1 = __builtin_amdgcn_mfma_f32_16x16x32_bf16(a1, bfr, acc1, 0, 0, 0);
        }
        float sc = scb[o], bi = scb[64 + o];
        float* ob = out + (size_t)n * 204800 + (size_t)o * 3200 + t * 25;
        #pragma unroll
        for (int reg = 0; reg < 4; ++reg) {
            int v = 4 * g + reg;                       // 0..15, always valid
            float val = acc0[reg] * sc + bi + xv[v * 68 + o];
            ob[v] = fmaxf(val, 0.f);
        }
        #pragma unroll
        for (int reg = 0; reg < 4; ++reg) {
            int v = 16 + 4 * g + reg;
            if (v < VV) {
                float val = acc1[reg] * sc + bi + xv[v * 68 + o];
                ob[v] = fmaxf(val, 0.f);
            }
        }
    }
}

extern "C" void kernel_launch(void* const* d_in, const int* in_sizes, int n_in,
                              void* d_out, int out_size, void* d_ws, size_t ws_size,
                              hipStream_t stream) {
    const float* x      = (const float*)d_in[0];
    const float* PA     = (const float*)d_in[1];
    const float* ln_g   = (const float*)d_in[2];
    const float* ln_b   = (const float*)d_in[3];
    const float* Wqk    = (const float*)d_in[4];
    const float* bqk    = (const float*)d_in[5];
    const float* conv_w = (const float*)d_in[6];
    const float* conv_b = (const float*)d_in[7];
    const float* bn_g   = (const float*)d_in[8];
    const float* bn_b   = (const float*)d_in[9];
    const float* bn_m   = (const float*)d_in[10];
    const float* bn_v   = (const float*)d_in[11];
    float* outp = (float*)d_out;

    agcn_fused_kernel<<<dim3(128 * TT), dim3(256), 0, stream>>>(
        x, PA, ln_g, ln_b, Wqk, bqk, conv_w, conv_b,
        bn_g, bn_b, bn_m, bn_v, outp);
}

// Round 4
// 248.276 us; speedup vs baseline: 2.9790x; 2.9790x over previous
//
#include <hip/hip_runtime.h>
#include <hip/hip_bf16.h>
#include <math.h>

typedef __attribute__((ext_vector_type(8))) short bf16x8;
typedef __attribute__((ext_vector_type(4))) float f32x4;

__device__ inline unsigned short f2bf(float f) {
    return __builtin_bit_cast(unsigned short, __float2bfloat16(f));
}
__device__ inline float bf2f(unsigned short u) {
    return __bfloat162float(__builtin_bit_cast(__hip_bfloat16, u));
}
__device__ inline bf16x8 cvt8(float4 a, float4 b) {
    bf16x8 r;
    r[0]=(short)f2bf(a.x); r[1]=(short)f2bf(a.y); r[2]=(short)f2bf(a.z); r[3]=(short)f2bf(a.w);
    r[4]=(short)f2bf(b.x); r[5]=(short)f2bf(b.y); r[6]=(short)f2bf(b.z); r[7]=(short)f2bf(b.w);
    return r;
}
__device__ inline void split8(float4 a, float4 b, bf16x8& hi, bf16x8& lo) {
    float f[8] = {a.x,a.y,a.z,a.w,b.x,b.y,b.z,b.w};
    #pragma unroll
    for (int i = 0; i < 8; ++i) {
        unsigned short h = f2bf(f[i]);
        hi[i] = (short)h;
        lo[i] = (short)f2bf(f[i] - bf2f(h));
    }
}

// LDS map (float units):
//  xv    f32 [25][65]            @0     (alloc 1628)
//  yn_hi bf16 [32][64] swizzled  @1628  (1024)   } overlay: A_bf u16 [80][40] @1628 (p4+)
//  yn_lo bf16 [32][64] swizzled  @2652  (1024)   }
//  qkb   f32 [25][52]            @3676  (1356)   overlay: xvT u16 [64][40] (p4+)
//  Abuf  f32 [3][625]            @5032  (2500)   overlay: zA u16 [25][200] (p5+)
// total 7532 floats = 30128 B -> 5 blocks/CU
#define LDS_FLOATS 7532

__global__ __launch_bounds__(256, 5)
void agcn_fused_kernel(const float* __restrict__ x,
                       const float* __restrict__ PA,
                       const float* __restrict__ ln_g, const float* __restrict__ ln_b,
                       const float* __restrict__ Wqk, const float* __restrict__ bqk,
                       const float* __restrict__ conv_w, const float* __restrict__ conv_b,
                       const float* __restrict__ bn_g, const float* __restrict__ bn_b,
                       const float* __restrict__ bn_m, const float* __restrict__ bn_v,
                       float* __restrict__ out)
{
    __shared__ float lds[LDS_FLOATS];
    float* xv = lds;                                        // [25][65]
    unsigned short* yn_hi = (unsigned short*)(lds + 1628);  // [32][64] swz
    unsigned short* yn_lo = (unsigned short*)(lds + 2652);
    unsigned short* A_bf  = (unsigned short*)(lds + 1628);  // [80][40]
    float* qkb  = lds + 3676;                               // [25][52]
    unsigned short* xvT = (unsigned short*)(lds + 3676);    // [64][40]
    float* Abuf = lds + 5032;                               // [3][625]
    unsigned short* zA  = (unsigned short*)(lds + 5032);    // [25][200]

    const int bid = blockIdx.x;
    const int n = bid >> 7, t = bid & 127;
    const int tid = threadIdx.x;
    const int lane = tid & 63, w = tid >> 6;
    const int g = lane >> 4, l15 = lane & 15;

    // ================= prologue: issue ALL weight loads =================
    const int o = 16 * w + l15;          // this lane's conv output channel / qk col
    float4 cw_f[12];
    #pragma unroll
    for (int kt = 0; kt < 6; ++kt) {
        const float* wp = &conv_w[(kt >> 1) * 4096 + o * 64 + (kt & 1) * 32 + 8 * g];
        cw_f[2*kt]   = *(const float4*)wp;
        cw_f[2*kt+1] = *(const float4*)(wp + 4);
    }
    float4 wq_f[4];
    float bq = 0.f;
    if (w < 3) {
        const int j = 16 * w + l15;
        #pragma unroll
        for (int ks = 0; ks < 2; ++ks) {
            const float* wp = &Wqk[j * 64 + ks * 32 + 8 * g];
            wq_f[2*ks]   = *(const float4*)wp;
            wq_f[2*ks+1] = *(const float4*)(wp + 4);
        }
        bq = bqk[j];
    }

    // ---- phase 0: stage x tile ----
    const float* xbase = x + (size_t)n * 204800 + t * 25;
    for (int idx = tid; idx < 1600; idx += 256) {
        int c = idx / 25, v = idx - c * 25;
        xv[v * 65 + c] = xbase[c * 3200 + v];
    }

    // convert weights to bf16 fragments (waits on prologue loads)
    bf16x8 cw[6];
    #pragma unroll
    for (int kt = 0; kt < 6; ++kt) cw[kt] = cvt8(cw_f[2*kt], cw_f[2*kt+1]);
    bf16x8 wqh[2], wql[2];
    if (w < 3) {
        #pragma unroll
        for (int ks = 0; ks < 2; ++ks) split8(wq_f[2*ks], wq_f[2*ks+1], wqh[ks], wql[ks]);
    }
    __syncthreads();

    // ---- phase 1: LayerNorm -> yn hi/lo (bf16, swizzled) ----
    {
        float lg = ln_g[lane], lb = ln_b[lane];
        for (int v = w; v < 25; v += 4) {
            float val = xv[v * 65 + lane];
            float s = val;
            for (int off = 32; off; off >>= 1) s += __shfl_xor(s, off);
            float mu = s * (1.0f / 64.0f);
            float d = val - mu;
            float s2 = d * d;
            for (int off = 32; off; off >>= 1) s2 += __shfl_xor(s2, off);
            float rstd = rsqrtf(s2 * (1.0f / 64.0f) + 1e-5f);
            float y = d * rstd * lg + lb;
            unsigned short h = f2bf(y);
            unsigned short l = f2bf(y - bf2f(h));
            int idx = (v * 64 + lane) ^ ((v & 7) << 3);
            yn_hi[idx] = h;
            yn_lo[idx] = l;
        }
    }
    __syncthreads();

    // ---- phase 2: qk MFMA (waves 0-2, nt = w): qkb[v][j] ----
    if (w < 3) {
        const int j = 16 * w + l15;
        #pragma unroll
        for (int mt = 0; mt < 2; ++mt) {
            f32x4 acc = {bq, bq, bq, bq};
            #pragma unroll
            for (int ks = 0; ks < 2; ++ks) {
                int row = 16 * mt + l15;
                int idx = (row * 64 + ks * 32 + 8 * g) ^ ((row & 7) << 3);
                bf16x8 ah = *(bf16x8*)&yn_hi[idx];
                bf16x8 al = *(bf16x8*)&yn_lo[idx];
                acc = __builtin_amdgcn_mfma_f32_16x16x32_bf16(al, wqh[ks], acc, 0, 0, 0);
                acc = __builtin_amdgcn_mfma_f32_16x16x32_bf16(ah, wql[ks], acc, 0, 0, 0);
                acc = __builtin_amdgcn_mfma_f32_16x16x32_bf16(ah, wqh[ks], acc, 0, 0, 0);
            }
            #pragma unroll
            for (int reg = 0; reg < 4; ++reg) {
                int v = 16 * mt + 4 * g + reg;
                if (v < 25) qkb[v * 52 + j] = acc[reg];
            }
        }
    }
    __syncthreads();

    // ---- phase 3: dots (fp32 VALU) ----
    for (int idx = tid; idx < 1875; idx += 256) {
        int h = idx / 625, r = idx - h * 625;
        int i = r / 25, j = r - i * 25;
        const float4* q = (const float4*)&qkb[i * 52 + h * 8];
        const float4* k = (const float4*)&qkb[j * 52 + 24 + h * 8];
        float4 q0 = q[0], q1 = q[1], k0 = k[0], k1 = k[1];
        float d = q0.x*k0.x + q0.y*k0.y + q0.z*k0.z + q0.w*k0.w
                + q1.x*k1.x + q1.y*k1.y + q1.z*k1.z + q1.w*k1.w;
        Abuf[idx] = d * 0.35355339059327373f;
    }
    __syncthreads();

    // ---- phase 4: softmax*PA -> A_bf ; xv -> xvT ----
    if (tid < 75) {
        int h = tid / 25, i = tid - h * 25;
        const float* row = &Abuf[h * 625 + i * 25];
        const float* pa = &PA[h * 625 + i * 25];
        float m = row[0];
        #pragma unroll
        for (int j = 1; j < 25; ++j) m = fmaxf(m, row[j]);
        float e[25];
        float s = 0.f;
        #pragma unroll
        for (int j = 0; j < 25; ++j) { e[j] = __expf(row[j] - m); s += e[j]; }
        float inv = 1.0f / s;
        unsigned short* ar = &A_bf[(h * 25 + i) * 40];
        #pragma unroll
        for (int j = 0; j < 25; ++j) ar[j] = f2bf(e[j] * inv * pa[j]);
        #pragma unroll
        for (int j = 25; j < 32; ++j) ar[j] = 0;
    }
    for (int idx = tid; idx < 2560; idx += 256) {
        int c = idx / 40, j = idx - c * 40;
        float val = (j < 25) ? xv[j * 65 + c] : 0.f;
        xvT[idx] = f2bf(val);
    }
    __syncthreads();

    // ---- phase 5: z MFMA -> zA[i][h*64+c] bf16 ----
    {
        bf16x8 bfrag = *(bf16x8*)&xvT[(16 * w + l15) * 40 + 8 * g];
        #pragma unroll
        for (int mt = 0; mt < 5; ++mt) {
            bf16x8 afrag = *(bf16x8*)&A_bf[(16 * mt + l15) * 40 + 8 * g];
            f32x4 zacc = {0.f, 0.f, 0.f, 0.f};
            zacc = __builtin_amdgcn_mfma_f32_16x16x32_bf16(afrag, bfrag, zacc, 0, 0, 0);
            #pragma unroll
            for (int reg = 0; reg < 4; ++reg) {
                int r = 16 * mt + 4 * g + reg;
                if (r < 75) {
                    int h = r / 25, i = r - h * 25;
                    zA[i * 200 + h * 64 + 16 * w + l15] = f2bf(zacc[reg]);
                }
            }
        }
    }
    __syncthreads();

    // ---- phase 6: conv MFMA + BN + residual + ReLU + store ----
    {
        // epilogue params (independent loads, issued before MFMAs)
        float bg = bn_g[o], bv = bn_v[o], bb = bn_b[o], bm = bn_m[o];
        float cb = conv_b[o] + conv_b[64 + o] + conv_b[128 + o];

        const int r1 = (16 + l15 < 25) ? (16 + l15) : 0;
        f32x4 acc0 = {0.f, 0.f, 0.f, 0.f}, acc1 = {0.f, 0.f, 0.f, 0.f};
        #pragma unroll
        for (int kt = 0; kt < 6; ++kt) {
            bf16x8 a0 = *(bf16x8*)&zA[l15 * 200 + 32 * kt + 8 * g];
            bf16x8 a1 = *(bf16x8*)&zA[r1 * 200 + 32 * kt + 8 * g];
            acc0 = __builtin_amdgcn_mfma_f32_16x16x32_bf16(a0, cw[kt], acc0, 0, 0, 0);
            acc1 = __builtin_amdgcn_mfma_f32_16x16x32_bf16(a1, cw[kt], acc1, 0, 0, 0);
        }
        float sc = bg * rsqrtf(bv + 1e-5f);
        float bi = cb * sc + bb - bm * sc;
        float* ob = out + (size_t)n * 204800 + (size_t)o * 3200 + t * 25;
        #pragma unroll
        for (int reg = 0; reg < 4; ++reg) {
            int v = 4 * g + reg;
            float val = acc0[reg] * sc + bi + xv[v * 65 + o];
            ob[v] = fmaxf(val, 0.f);
        }
        #pragma unroll
        for (int reg = 0; reg < 4; ++reg) {
            int v = 16 + 4 * g + reg;
            if (v < 25) {
                float val = acc1[reg] * sc + bi + xv[v * 65 + o];
                ob[v] = fmaxf(val, 0.f);
            }
        }
    }
}

extern "C" void kernel_launch(void* const* d_in, const int* in_sizes, int n_in,
                              void* d_out, int out_size, void* d_ws, size_t ws_size,
                              hipStream_t stream) {
    const float* x      = (const float*)d_in[0];
    const float* PA     = (const float*)d_in[1];
    const float* ln_g   = (const float*)d_in[2];
    const float* ln_b   = (const float*)d_in[3];
    const float* Wqk    = (const float*)d_in[4];
    const float* bqk    = (const float*)d_in[5];
    const float* conv_w = (const float*)d_in[6];
    const float* conv_b = (const float*)d_in[7];
    const float* bn_g   = (const float*)d_in[8];
    const float* bn_b   = (const float*)d_in[9];
    const float* bn_m   = (const float*)d_in[10];
    const float* bn_v   = (const float*)d_in[11];
    float* outp = (float*)d_out;

    agcn_fused_kernel<<<dim3(128 * 128), dim3(256), 0, stream>>>(
        x, PA, ln_g, ln_b, Wqk, bqk, conv_w, conv_b,
        bn_g, bn_b, bn_m, bn_v, outp);
}

// Round 5
// 247.954 us; speedup vs baseline: 2.9829x; 1.0013x over previous
//
#include <hip/hip_runtime.h>
#include <hip/hip_bf16.h>
#include <math.h>

typedef __attribute__((ext_vector_type(8))) short bf16x8;
typedef __attribute__((ext_vector_type(4))) float f32x4;

__device__ inline unsigned short f2bf(float f) {
    return __builtin_bit_cast(unsigned short, __float2bfloat16(f));
}
__device__ inline float bf2f(unsigned short u) {
    return __bfloat162float(__builtin_bit_cast(__hip_bfloat16, u));
}
__device__ inline bf16x8 cvt8(float4 a, float4 b) {
    bf16x8 r;
    r[0]=(short)f2bf(a.x); r[1]=(short)f2bf(a.y); r[2]=(short)f2bf(a.z); r[3]=(short)f2bf(a.w);
    r[4]=(short)f2bf(b.x); r[5]=(short)f2bf(b.y); r[6]=(short)f2bf(b.z); r[7]=(short)f2bf(b.w);
    return r;
}
__device__ inline void split8(float4 a, float4 b, bf16x8& hi, bf16x8& lo) {
    float f[8] = {a.x,a.y,a.z,a.w,b.x,b.y,b.z,b.w};
    #pragma unroll
    for (int i = 0; i < 8; ++i) {
        unsigned short h = f2bf(f[i]);
        hi[i] = (short)h;
        lo[i] = (short)f2bf(f[i] - bf2f(h));
    }
}

// LDS map (float idx units; total 6403 fl = 25612 B -> 6 blocks/CU):
//  xv   f32 [25][65]          @0      p0..end
//  ynh  u16 logical[32][64]sw @1628   p1-2 (rows>=25 spill-read into ynl: garbage, rows discarded)
//  ynl  u16 logical[32][64]sw @2428   p1-2 (spill-read into qkb region: garbage, rows discarded)
//  A_bf u16 [80][40]          @1628   p4-5 (overlays ynh+ynl exactly, 6400 B)
//  qkb  f32 [25][52]          @3228   p2-3
//  xvT  u16 [64][40]          @3228   p4-5 (overlays qkb, 5120 B)
//  Abuf f32 [75][25]          @4528   p3-4
//  zA   u16 [25][200]         @1628   p6   (written after p5 drains, overlays A_bf+xvT)
//  res  f32 [64][25]          @4528   epilogue (overlays dead Abuf; disjoint from zA)
#define LDS_FLOATS 6403

__global__ __launch_bounds__(256, 6)
void agcn_fused_kernel(const float* __restrict__ x,
                       const float* __restrict__ PA,
                       const float* __restrict__ ln_g, const float* __restrict__ ln_b,
                       const float* __restrict__ Wqk, const float* __restrict__ bqk,
                       const float* __restrict__ conv_w, const float* __restrict__ conv_b,
                       const float* __restrict__ bn_g, const float* __restrict__ bn_b,
                       const float* __restrict__ bn_m, const float* __restrict__ bn_v,
                       float* __restrict__ out)
{
    __shared__ float lds[LDS_FLOATS];
    float* xv = lds;                                        // [25][65]
    unsigned short* ynh = (unsigned short*)(lds + 1628);
    unsigned short* ynl = (unsigned short*)(lds + 2428);
    unsigned short* A_bf = (unsigned short*)(lds + 1628);   // [80][40]
    float* qkb  = lds + 3228;                               // [25][52]
    unsigned short* xvT = (unsigned short*)(lds + 3228);    // [64][40]
    float* Abuf = lds + 4528;                               // [75][25]
    unsigned short* zA  = (unsigned short*)(lds + 1628);    // [25][200]
    float* res  = lds + 4528;                               // [64][25]

    // XCD-aware swizzle: contiguous slice ranges per XCD (16384 % 8 == 0, bijective)
    const int bid = blockIdx.x;
    const int sid = ((bid & 7) << 11) | (bid >> 3);
    const int n = sid >> 7, t = sid & 127;
    const int tid = threadIdx.x;
    const int lane = tid & 63, w = tid >> 6;
    const int g = lane >> 4, l15 = lane & 15;

    // ================= prologue: issue ALL weight loads =================
    const int o = 16 * w + l15;
    float4 cw_f[12];
    #pragma unroll
    for (int kt = 0; kt < 6; ++kt) {
        const float* wp = &conv_w[(kt >> 1) * 4096 + o * 64 + (kt & 1) * 32 + 8 * g];
        cw_f[2*kt]   = *(const float4*)wp;
        cw_f[2*kt+1] = *(const float4*)(wp + 4);
    }
    float4 wq_f[4];
    float bq = 0.f;
    if (w < 3) {
        const int j = 16 * w + l15;
        #pragma unroll
        for (int ks = 0; ks < 2; ++ks) {
            const float* wp = &Wqk[j * 64 + ks * 32 + 8 * g];
            wq_f[2*ks]   = *(const float4*)wp;
            wq_f[2*ks+1] = *(const float4*)(wp + 4);
        }
        bq = bqk[j];
    }

    // ---- phase 0: stage x tile ----
    const float* xbase = x + (size_t)n * 204800 + t * 25;
    for (int idx = tid; idx < 1600; idx += 256) {
        int c = idx / 25, v = idx - c * 25;
        xv[v * 65 + c] = xbase[c * 3200 + v];
    }

    bf16x8 cw[6];
    #pragma unroll
    for (int kt = 0; kt < 6; ++kt) cw[kt] = cvt8(cw_f[2*kt], cw_f[2*kt+1]);
    bf16x8 wqh[2], wql[2];
    if (w < 3) {
        #pragma unroll
        for (int ks = 0; ks < 2; ++ks) split8(wq_f[2*ks], wq_f[2*ks+1], wqh[ks], wql[ks]);
    }
    __syncthreads();

    // ---- phase 1: LayerNorm -> yn hi/lo (bf16, swizzled) ----
    {
        float lg = ln_g[lane], lb = ln_b[lane];
        for (int v = w; v < 25; v += 4) {
            float val = xv[v * 65 + lane];
            float s = val;
            for (int off = 32; off; off >>= 1) s += __shfl_xor(s, off);
            float mu = s * (1.0f / 64.0f);
            float d = val - mu;
            float s2 = d * d;
            for (int off = 32; off; off >>= 1) s2 += __shfl_xor(s2, off);
            float rstd = rsqrtf(s2 * (1.0f / 64.0f) + 1e-5f);
            float y = d * rstd * lg + lb;
            unsigned short h = f2bf(y);
            unsigned short l = f2bf(y - bf2f(h));
            int idx = (v * 64 + lane) ^ ((v & 7) << 3);
            ynh[idx] = h;
            ynl[idx] = l;
        }
    }
    __syncthreads();

    // ---- phase 2: qk MFMA (waves 0-2): qkb[v][j], 3-term hi/lo ----
    if (w < 3) {
        const int j = 16 * w + l15;
        #pragma unroll
        for (int mt = 0; mt < 2; ++mt) {
            f32x4 acc = {bq, bq, bq, bq};
            #pragma unroll
            for (int ks = 0; ks < 2; ++ks) {
                int row = 16 * mt + l15;
                int idx = (row * 64 + ks * 32 + 8 * g) ^ ((row & 7) << 3);
                bf16x8 ah = *(bf16x8*)&ynh[idx];
                bf16x8 al = *(bf16x8*)&ynl[idx];
                acc = __builtin_amdgcn_mfma_f32_16x16x32_bf16(al, wqh[ks], acc, 0, 0, 0);
                acc = __builtin_amdgcn_mfma_f32_16x16x32_bf16(ah, wql[ks], acc, 0, 0, 0);
                acc = __builtin_amdgcn_mfma_f32_16x16x32_bf16(ah, wqh[ks], acc, 0, 0, 0);
            }
            #pragma unroll
            for (int reg = 0; reg < 4; ++reg) {
                int v = 16 * mt + 4 * g + reg;
                if (v < 25) qkb[v * 52 + j] = acc[reg];
            }
        }
    }
    __syncthreads();

    // ---- phase 3: dots (fp32 VALU) ----
    for (int idx = tid; idx < 1875; idx += 256) {
        int h = idx / 625, r = idx - h * 625;
        int i = r / 25, j = r - i * 25;
        const float4* q = (const float4*)&qkb[i * 52 + h * 8];
        const float4* k = (const float4*)&qkb[j * 52 + 24 + h * 8];
        float4 q0 = q[0], q1 = q[1], k0 = k[0], k1 = k[1];
        float d = q0.x*k0.x + q0.y*k0.y + q0.z*k0.z + q0.w*k0.w
                + q1.x*k1.x + q1.y*k1.y + q1.z*k1.z + q1.w*k1.w;
        Abuf[idx] = d * 0.35355339059327373f;
    }
    __syncthreads();

    // ---- phase 4: softmax*PA -> A_bf ; xv -> xvT ----
    if (tid < 75) {
        int h = tid / 25, i = tid - h * 25;
        const float* row = &Abuf[h * 625 + i * 25];
        const float* pa = &PA[h * 625 + i * 25];
        float m = row[0];
        #pragma unroll
        for (int j = 1; j < 25; ++j) m = fmaxf(m, row[j]);
        float e[25];
        float s = 0.f;
        #pragma unroll
        for (int j = 0; j < 25; ++j) { e[j] = __expf(row[j] - m); s += e[j]; }
        float inv = 1.0f / s;
        unsigned short* ar = &A_bf[(h * 25 + i) * 40];
        #pragma unroll
        for (int j = 0; j < 25; ++j) ar[j] = f2bf(e[j] * inv * pa[j]);
        #pragma unroll
        for (int j = 25; j < 32; ++j) ar[j] = 0;
    }
    for (int idx = tid; idx < 2560; idx += 256) {
        int c = idx / 40, j = idx - c * 40;
        float val = (j < 25) ? xv[j * 65 + c] : 0.f;
        xvT[idx] = f2bf(val);
    }
    __syncthreads();

    // ---- phase 5: z MFMA -> registers (zA deferred past barrier) ----
    f32x4 zacc[5];
    {
        bf16x8 bfrag = *(bf16x8*)&xvT[(16 * w + l15) * 40 + 8 * g];
        #pragma unroll
        for (int mt = 0; mt < 5; ++mt) {
            bf16x8 afrag = *(bf16x8*)&A_bf[(16 * mt + l15) * 40 + 8 * g];
            f32x4 a = {0.f, 0.f, 0.f, 0.f};
            zacc[mt] = __builtin_amdgcn_mfma_f32_16x16x32_bf16(afrag, bfrag, a, 0, 0, 0);
        }
    }
    __syncthreads();   // all p5 frag reads drained; A_bf/xvT now dead

    // ---- write zA over dead A_bf/xvT region ----
    #pragma unroll
    for (int mt = 0; mt < 5; ++mt) {
        #pragma unroll
        for (int reg = 0; reg < 4; ++reg) {
            int r = 16 * mt + 4 * g + reg;
            if (r < 75) {
                int h = r / 25, i = r - h * 25;
                zA[i * 200 + h * 64 + 16 * w + l15] = f2bf(zacc[mt][reg]);
            }
        }
    }
    __syncthreads();

    // ---- phase 6: conv MFMA + BN + residual + ReLU -> res ----
    {
        float bg = bn_g[o], bv = bn_v[o], bb = bn_b[o], bm = bn_m[o];
        float cb = conv_b[o] + conv_b[64 + o] + conv_b[128 + o];

        const int r1 = (16 + l15 < 25) ? (16 + l15) : 0;
        f32x4 acc0 = {0.f, 0.f, 0.f, 0.f}, acc1 = {0.f, 0.f, 0.f, 0.f};
        #pragma unroll
        for (int kt = 0; kt < 6; ++kt) {
            bf16x8 a0 = *(bf16x8*)&zA[l15 * 200 + 32 * kt + 8 * g];
            bf16x8 a1 = *(bf16x8*)&zA[r1 * 200 + 32 * kt + 8 * g];
            acc0 = __builtin_amdgcn_mfma_f32_16x16x32_bf16(a0, cw[kt], acc0, 0, 0, 0);
            acc1 = __builtin_amdgcn_mfma_f32_16x16x32_bf16(a1, cw[kt], acc1, 0, 0, 0);
        }
        float sc = bg * rsqrtf(bv + 1e-5f);
        float bi = cb * sc + bb - bm * sc;
        #pragma unroll
        for (int reg = 0; reg < 4; ++reg) {
            int v = 4 * g + reg;
            float val = acc0[reg] * sc + bi + xv[v * 65 + o];
            res[o * 25 + v] = fmaxf(val, 0.f);
        }
        #pragma unroll
        for (int reg = 0; reg < 4; ++reg) {
            int v = 16 + 4 * g + reg;
            if (v < 25) {
                float val = acc1[reg] * sc + bi + xv[v * 65 + o];
                res[o * 25 + v] = fmaxf(val, 0.f);
            }
        }
    }
    __syncthreads();

    // ---- coalesced store ----
    {
        float* ob = out + (size_t)n * 204800 + t * 25;
        for (int idx = tid; idx < 1600; idx += 256) {
            int c = idx / 25, v = idx - c * 25;
            ob[c * 3200 + v] = res[idx];
        }
    }
}

extern "C" void kernel_launch(void* const* d_in, const int* in_sizes, int n_in,
                              void* d_out, int out_size, void* d_ws, size_t ws_size,
                              hipStream_t stream) {
    const float* x      = (const float*)d_in[0];
    const float* PA     = (const float*)d_in[1];
    const float* ln_g   = (const float*)d_in[2];
    const float* ln_b   = (const float*)d_in[3];
    const float* Wqk    = (const float*)d_in[4];
    const float* bqk    = (const float*)d_in[5];
    const float* conv_w = (const float*)d_in[6];
    const float* conv_b = (const float*)d_in[7];
    const float* bn_g   = (const float*)d_in[8];
    const float* bn_b   = (const float*)d_in[9];
    const float* bn_m   = (const float*)d_in[10];
    const float* bn_v   = (const float*)d_in[11];
    float* outp = (float*)d_out;

    agcn_fused_kernel<<<dim3(128 * 128), dim3(256), 0, stream>>>(
        x, PA, ln_g, ln_b, Wqk, bqk, conv_w, conv_b,
        bn_g, bn_b, bn_m, bn_v, outp);
}